// Round 3
// baseline (54.187 us; speedup 1.0000x reference)
//
#include <hip/hip_runtime.h>
#include <math.h>

// out[r, v] = sin(x[r] * freqs[v]),  r in [0, 64*4096), v in [0, 256)
// freqs[v] = 10^(min(v,127)/127 * 4)
//
// One wave per 4 rows: one float4 broadcast-load of x covers 4 rows; lane l
// covers v = 4l..4l+3 and does one 16B nontemporal store per row
// (64 lanes * 16 B = 1024 B contiguous per row). sin via hardware v_sin_f32
// (revolution input): c[v] = freqs[v]/(2*pi) precomputed in f64 per thread.

typedef float f32x4 __attribute__((ext_vector_type(4)));

__global__ __launch_bounds__(256) void InputLayer_57337813401914_kernel(
    const float* __restrict__ x, float* __restrict__ out, int rows) {
  const int lane = threadIdx.x & 63;
  const int gwave = (int)((blockIdx.x * blockDim.x + threadIdx.x) >> 6);
  const int nwaves = (int)((gridDim.x * blockDim.x) >> 6);

  // Per-thread frequency constants (freq / 2pi), computed once in f64.
  float c[4];
#pragma unroll
  for (int j = 0; j < 4; ++j) {
    int v = 4 * lane + j;
    int idx = v < 128 ? v : 127;
    double e = (double)idx * (4.0 / 127.0);
    double f = pow(10.0, e);
    c[j] = (float)(f * 0.15915494309189535);  // f / (2*pi)
  }

  const int ngroups = rows >> 2;  // 4 rows per group
  for (int g = gwave; g < ngroups; g += nwaves) {
    // All 64 lanes load the same 16 B -> broadcast; covers rows 4g..4g+3.
    f32x4 xq = *reinterpret_cast<const f32x4*>(x + (size_t)g * 4);
    float* base = out + ((size_t)g * 4) * 256 + (size_t)lane * 4;
#pragma unroll
    for (int k = 0; k < 4; ++k) {
      float xv = xq[k];  // static index (unrolled) -> stays in registers
      f32x4 o;
      o.x = __builtin_amdgcn_sinf(__builtin_amdgcn_fractf(xv * c[0]));
      o.y = __builtin_amdgcn_sinf(__builtin_amdgcn_fractf(xv * c[1]));
      o.z = __builtin_amdgcn_sinf(__builtin_amdgcn_fractf(xv * c[2]));
      o.w = __builtin_amdgcn_sinf(__builtin_amdgcn_fractf(xv * c[3]));
      __builtin_nontemporal_store(o, reinterpret_cast<f32x4*>(base + (size_t)k * 256));
    }
  }
}

extern "C" void kernel_launch(void* const* d_in, const int* in_sizes, int n_in,
                              void* d_out, int out_size, void* d_ws, size_t ws_size,
                              hipStream_t stream) {
  const float* x = (const float*)d_in[0];
  float* out = (float*)d_out;
  const int rows = in_sizes[0];  // 64 * 4096 = 262144

  const int block = 256;
  const int grid = 2048;  // 8192 waves; 65536 groups -> 8 groups/wave
  InputLayer_57337813401914_kernel<<<grid, block, 0, stream>>>(x, out, rows);
}

// Round 4
// 46.810 us; speedup vs baseline: 1.1576x; 1.1576x over previous
//
#include <hip/hip_runtime.h>
#include <math.h>

// out[r, v] = sin(x[r] * freqs[v]),  r in [0, 64*4096), v in [0, 256)
// freqs[v] = 10^(min(v,127)/127 * 4)
//
// One wave per 4 rows: one float4 broadcast-load of x covers 4 rows; lane l
// covers v = 4l..4l+3 and does one 16B cached store per row
// (64 lanes * 16 B = 1024 B contiguous per row). sin via hardware v_sin_f32
// (revolution input): c[v] = freqs[v]/(2*pi) precomputed in f64 per thread.
// R3 lesson: nontemporal stores REGRESSED (54.2 vs 49.9 us) -- normal
// write-back L2 handles the full-line streaming writes better. Keep cached.

typedef float f32x4 __attribute__((ext_vector_type(4)));

__global__ __launch_bounds__(256) void InputLayer_57337813401914_kernel(
    const float* __restrict__ x, float* __restrict__ out, int rows) {
  const int lane = threadIdx.x & 63;
  const int gwave = (int)((blockIdx.x * blockDim.x + threadIdx.x) >> 6);
  const int nwaves = (int)((gridDim.x * blockDim.x) >> 6);

  // Per-thread frequency constants (freq / 2pi), computed once in f64.
  float c[4];
#pragma unroll
  for (int j = 0; j < 4; ++j) {
    int v = 4 * lane + j;
    int idx = v < 128 ? v : 127;
    double e = (double)idx * (4.0 / 127.0);
    double f = pow(10.0, e);
    c[j] = (float)(f * 0.15915494309189535);  // f / (2*pi)
  }

  const int ngroups = rows >> 2;  // 4 rows per group
  for (int g = gwave; g < ngroups; g += nwaves) {
    // All 64 lanes load the same 16 B -> broadcast; covers rows 4g..4g+3.
    f32x4 xq = *reinterpret_cast<const f32x4*>(x + (size_t)g * 4);
    float* base = out + ((size_t)g * 4) * 256 + (size_t)lane * 4;
#pragma unroll
    for (int k = 0; k < 4; ++k) {
      float xv = xq[k];  // static index (unrolled) -> stays in registers
      f32x4 o;
      o.x = __builtin_amdgcn_sinf(__builtin_amdgcn_fractf(xv * c[0]));
      o.y = __builtin_amdgcn_sinf(__builtin_amdgcn_fractf(xv * c[1]));
      o.z = __builtin_amdgcn_sinf(__builtin_amdgcn_fractf(xv * c[2]));
      o.w = __builtin_amdgcn_sinf(__builtin_amdgcn_fractf(xv * c[3]));
      *reinterpret_cast<f32x4*>(base + (size_t)k * 256) = o;
    }
  }
}

extern "C" void kernel_launch(void* const* d_in, const int* in_sizes, int n_in,
                              void* d_out, int out_size, void* d_ws, size_t ws_size,
                              hipStream_t stream) {
  const float* x = (const float*)d_in[0];
  float* out = (float*)d_out;
  const int rows = in_sizes[0];  // 64 * 4096 = 262144

  const int block = 256;
  const int grid = 2048;  // 8192 waves; 65536 groups -> 8 groups/wave
  InputLayer_57337813401914_kernel<<<grid, block, 0, stream>>>(x, out, rows);
}